// Round 1
// baseline (942.290 us; speedup 1.0000x reference)
//
#include <hip/hip_runtime.h>
#include <cstdint>

// Problem constants (fixed by the reference): out = sign(x) @ (sign(fp_c)*alpha)^T + bias
#define B_SZ   16384
#define IN_SZ  4096
#define OUT_SZ 4096

typedef int   int4v   __attribute__((ext_vector_type(4)));

__device__ __forceinline__ int sgn8(float v) { return (v > 0.f) - (v < 0.f); }

// ---------------- weight prep: one block (256 thr) per output row ----------------
// Computes: mean of row, wb = sign(fp - mean) as int8, alpha = mean(min(|fp-mean|,1))
__global__ __launch_bounds__(256) void wprep_kernel(const float* __restrict__ fp,
                                                    int8_t* __restrict__ wb,
                                                    float* __restrict__ alpha) {
    __shared__ float red[4];
    const int o = blockIdx.x;
    const int t = threadIdx.x;
    const float4* row = (const float4*)(fp + (size_t)o * IN_SZ);   // 1024 float4 per row

    float4 v[4];
    float s = 0.f;
#pragma unroll
    for (int i = 0; i < 4; ++i) {
        v[i] = row[t + i * 256];                                    // coalesced
        s += (v[i].x + v[i].y) + (v[i].z + v[i].w);
    }
#pragma unroll
    for (int off = 32; off > 0; off >>= 1) s += __shfl_down(s, off, 64);
    if ((t & 63) == 0) red[t >> 6] = s;
    __syncthreads();
    const float mean = (red[0] + red[1] + red[2] + red[3]) * (1.f / IN_SZ);
    __syncthreads();

    int* wrow = (int*)(wb + (size_t)o * IN_SZ);                     // 1024 ints per row
    float a = 0.f;
#pragma unroll
    for (int i = 0; i < 4; ++i) {
        const float dx = v[i].x - mean, dy = v[i].y - mean;
        const float dz = v[i].z - mean, dw = v[i].w - mean;
        a += fminf(fabsf(dx), 1.f) + fminf(fabsf(dy), 1.f)
           + fminf(fabsf(dz), 1.f) + fminf(fabsf(dw), 1.f);
        const int p = (sgn8(dx) & 0xff) | ((sgn8(dy) & 0xff) << 8)
                    | ((sgn8(dz) & 0xff) << 16) | (sgn8(dw) << 24);
        wrow[t + i * 256] = p;                                      // coalesced
    }
#pragma unroll
    for (int off = 32; off > 0; off >>= 1) a += __shfl_down(a, off, 64);
    if ((t & 63) == 0) red[t >> 6] = a;
    __syncthreads();
    if (t == 0) alpha[o] = (red[0] + red[1] + red[2] + red[3]) * (1.f / IN_SZ);
}

// ---------------- activation prep: sign(x) -> int8, one float4 per thread ----------------
__global__ __launch_bounds__(256) void xprep_kernel(const float* __restrict__ x,
                                                    int8_t* __restrict__ xb) {
    const size_t i = (size_t)blockIdx.x * 256 + threadIdx.x;
    const float4 v = ((const float4*)x)[i];
    const int p = (sgn8(v.x) & 0xff) | ((sgn8(v.y) & 0xff) << 8)
                | ((sgn8(v.z) & 0xff) << 16) | (sgn8(v.w) << 24);
    ((int*)xb)[i] = p;
}

// ---------------- i8 binary GEMM: C[b,o] = alpha[o] * (Xb . Wb[o]) + bias[o] ----------------
// m97 ladder structure: 128x128 block tile, BK=64, 4 waves, 4x4 frags of 16x16x64 per wave,
// global_load_lds width=16 staging. LDS layout row-linear (NO padding — required by the
// wave-uniform-base + lane*16 semantics of global_load_lds).
__global__ __launch_bounds__(256) void gemm_kernel(const int8_t* __restrict__ Xb,
                                                   const int8_t* __restrict__ Wb,
                                                   const float* __restrict__ alpha,
                                                   const float* __restrict__ bias,
                                                   float* __restrict__ out) {
    __shared__ __align__(16) int8_t As[128 * 64];   // 8 KB
    __shared__ __align__(16) int8_t Bs[128 * 64];   // 8 KB

    const int tid  = threadIdx.x;
    const int lane = tid & 63;
    const int wave = tid >> 6;
    const int tm = blockIdx.x;          // 128 tiles along B
    const int tn = blockIdx.y;          // 32 tiles along OUT
    const int wm = (wave >> 1) * 64;    // wave's 64x64 sub-tile
    const int wn = (wave & 1) * 64;

    // staging: each wave stages 32 rows of each tile, 2 instrs x (16 rows x 64B = 1024B)
    const int srow = lane >> 2;          // 0..15
    const int scol = (lane & 3) * 16;    // 0,16,32,48
    const int8_t* gA = Xb + (size_t)(tm * 128 + wave * 32 + srow) * IN_SZ + scol;
    const int8_t* gB = Wb + (size_t)(tn * 128 + wave * 32 + srow) * IN_SZ + scol;

    int4v acc[4][4] = {};                // zero-init accumulators (64 VGPRs)

    const int lrow = lane & 15;          // fragment row (m / n)
    const int lq16 = (lane >> 4) * 16;   // fragment k-offset (quad * 16 bytes)

    for (int k0 = 0; k0 < IN_SZ; k0 += 64) {
#pragma unroll
        for (int j = 0; j < 2; ++j) {
            __builtin_amdgcn_global_load_lds(
                (const __attribute__((address_space(1))) uint32_t*)(gA + k0 + (size_t)j * 16 * IN_SZ),
                (__attribute__((address_space(3))) uint32_t*)(As + (wave * 32 + j * 16) * 64),
                16, 0, 0);
            __builtin_amdgcn_global_load_lds(
                (const __attribute__((address_space(1))) uint32_t*)(gB + k0 + (size_t)j * 16 * IN_SZ),
                (__attribute__((address_space(3))) uint32_t*)(Bs + (wave * 32 + j * 16) * 64),
                16, 0, 0);
        }
        __syncthreads();   // compiler emits vmcnt(0) drain before barrier → staging complete

        int4v a[4], b[4];
#pragma unroll
        for (int i = 0; i < 4; ++i) {
            a[i] = *(const int4v*)(As + (wm + i * 16 + lrow) * 64 + lq16);
            b[i] = *(const int4v*)(Bs + (wn + i * 16 + lrow) * 64 + lq16);
        }
#pragma unroll
        for (int i = 0; i < 4; ++i)
#pragma unroll
            for (int j = 0; j < 4; ++j)
                acc[i][j] = __builtin_amdgcn_mfma_i32_16x16x64_i8(a[i], b[j], acc[i][j], 0, 0, 0);
        __syncthreads();
    }

    // epilogue: C/D 16x16 layout col=lane&15, row=(lane>>4)*4+reg (dtype-independent)
    const int col  = lane & 15;
    const int rowq = (lane >> 4) * 4;
#pragma unroll
    for (int j = 0; j < 4; ++j) {
        const int o = tn * 128 + wn + j * 16 + col;
        const float al = alpha[o];
        const float bi = bias[o];
#pragma unroll
        for (int i = 0; i < 4; ++i) {
            const size_t m = (size_t)(tm * 128 + wm + i * 16 + rowq);
#pragma unroll
            for (int r = 0; r < 4; ++r)
                out[(m + r) * OUT_SZ + o] = al * (float)acc[i][j][r] + bi;
        }
    }
}

extern "C" void kernel_launch(void* const* d_in, const int* in_sizes, int n_in,
                              void* d_out, int out_size, void* d_ws, size_t ws_size,
                              hipStream_t stream) {
    const float* x    = (const float*)d_in[0];   // [B, IN] fp32
    const float* fp   = (const float*)d_in[1];   // [OUT, IN] fp32
    const float* bias = (const float*)d_in[2];   // [OUT] fp32
    float* out = (float*)d_out;                  // [B, OUT] fp32

    // workspace layout: xb (64 MiB) | wb (16 MiB) | alpha (16 KiB)  ~= 80 MiB
    int8_t* xb    = (int8_t*)d_ws;
    int8_t* wb    = xb + (size_t)B_SZ * IN_SZ;
    float*  alpha = (float*)(wb + (size_t)OUT_SZ * IN_SZ);

    hipLaunchKernelGGL(wprep_kernel, dim3(OUT_SZ), dim3(256), 0, stream, fp, wb, alpha);
    hipLaunchKernelGGL(xprep_kernel, dim3(B_SZ * IN_SZ / 1024), dim3(256), 0, stream, x, xb);
    hipLaunchKernelGGL(gemm_kernel, dim3(B_SZ / 128, OUT_SZ / 128), dim3(256), 0, stream,
                       xb, wb, alpha, bias, out);
}

// Round 2
// 813.993 us; speedup vs baseline: 1.1576x; 1.1576x over previous
//
#include <hip/hip_runtime.h>
#include <cstdint>

// out = sign(x) @ (sign(fp - rowmean)*alpha)^T + bias ; exact i8 binary GEMM via MFMA
#define B_SZ   16384
#define IN_SZ  4096
#define OUT_SZ 4096

typedef int int4v  __attribute__((ext_vector_type(4)));
typedef int int16v __attribute__((ext_vector_type(16)));

__device__ __forceinline__ int sgn8(float v) { return (v > 0.f) - (v < 0.f); }

// ---------------- weight prep: one block (256 thr) per output row ----------------
__global__ __launch_bounds__(256) void wprep_kernel(const float* __restrict__ fp,
                                                    int8_t* __restrict__ wb,
                                                    float* __restrict__ alpha) {
    __shared__ float red[4];
    const int o = blockIdx.x;
    const int t = threadIdx.x;
    const float4* row = (const float4*)(fp + (size_t)o * IN_SZ);

    float4 v[4];
    float s = 0.f;
#pragma unroll
    for (int i = 0; i < 4; ++i) {
        v[i] = row[t + i * 256];
        s += (v[i].x + v[i].y) + (v[i].z + v[i].w);
    }
#pragma unroll
    for (int off = 32; off > 0; off >>= 1) s += __shfl_down(s, off, 64);
    if ((t & 63) == 0) red[t >> 6] = s;
    __syncthreads();
    const float mean = (red[0] + red[1] + red[2] + red[3]) * (1.f / IN_SZ);
    __syncthreads();

    int* wrow = (int*)(wb + (size_t)o * IN_SZ);
    float a = 0.f;
#pragma unroll
    for (int i = 0; i < 4; ++i) {
        const float dx = v[i].x - mean, dy = v[i].y - mean;
        const float dz = v[i].z - mean, dw = v[i].w - mean;
        a += fminf(fabsf(dx), 1.f) + fminf(fabsf(dy), 1.f)
           + fminf(fabsf(dz), 1.f) + fminf(fabsf(dw), 1.f);
        const int p = (sgn8(dx) & 0xff) | ((sgn8(dy) & 0xff) << 8)
                    | ((sgn8(dz) & 0xff) << 16) | (sgn8(dw) << 24);
        wrow[t + i * 256] = p;
    }
#pragma unroll
    for (int off = 32; off > 0; off >>= 1) a += __shfl_down(a, off, 64);
    if ((t & 63) == 0) red[t >> 6] = a;
    __syncthreads();
    if (t == 0) alpha[o] = (red[0] + red[1] + red[2] + red[3]) * (1.f / IN_SZ);
}

// ---------------- activation prep: sign(x) -> int8, 2 float4 per thread ----------------
__global__ __launch_bounds__(256) void xprep_kernel(const float* __restrict__ x,
                                                    int8_t* __restrict__ xb) {
    const size_t i = ((size_t)blockIdx.x * 256 + threadIdx.x) * 2;
    const float4 v0 = ((const float4*)x)[i];
    const float4 v1 = ((const float4*)x)[i + 1];
    int2 p;
    p.x = (sgn8(v0.x) & 0xff) | ((sgn8(v0.y) & 0xff) << 8)
        | ((sgn8(v0.z) & 0xff) << 16) | (sgn8(v0.w) << 24);
    p.y = (sgn8(v1.x) & 0xff) | ((sgn8(v1.y) & 0xff) << 8)
        | ((sgn8(v1.z) & 0xff) << 16) | (sgn8(v1.w) << 24);
    ((int2*)xb)[i / 2] = p;
}

// ---------------- i8 binary GEMM, 32x32x32 MFMA ----------------
// Block 128x128, BK=64, 4 waves in 2x2 of 64x64 wave tiles, 2x2 frags of 32x32 per wave.
// LDS row-linear 64B rows (required by global_load_lds wave-uniform-base semantics).
// __launch_bounds__(256,4): force <=128 regs/wave -> 4 blocks/CU residency.
__global__ __launch_bounds__(256, 4) void gemm_kernel(const int8_t* __restrict__ Xb,
                                                      const int8_t* __restrict__ Wb,
                                                      const float* __restrict__ alpha,
                                                      const float* __restrict__ bias,
                                                      float* __restrict__ out) {
    __shared__ __align__(16) int8_t As[128 * 64];   // 8 KB
    __shared__ __align__(16) int8_t Bs[128 * 64];   // 8 KB

    const int tid  = threadIdx.x;
    const int lane = tid & 63;
    const int wave = tid >> 6;
    const int tm = blockIdx.x;          // 128 tiles along B
    const int tn = blockIdx.y;          // 32 tiles along OUT
    const int wm = (wave >> 1) * 64;
    const int wn = (wave & 1) * 64;

    // staging: each wave stages 32 rows of each tile: 2 x (16 rows x 64B)
    const int srow = lane >> 2;
    const int scol = (lane & 3) * 16;
    const int8_t* gA = Xb + (size_t)(tm * 128 + wave * 32 + srow) * IN_SZ + scol;
    const int8_t* gB = Wb + (size_t)(tn * 128 + wave * 32 + srow) * IN_SZ + scol;

    int16v acc[2][2] = {};               // 64 AGPRs

    const int frow = lane & 31;          // fragment row (m / n)
    const int fk   = (lane >> 5) * 16;   // k-byte offset within 32B half

    for (int k0 = 0; k0 < IN_SZ; k0 += 64) {
#pragma unroll
        for (int j = 0; j < 2; ++j) {
            __builtin_amdgcn_global_load_lds(
                (const __attribute__((address_space(1))) uint32_t*)(gA + k0 + (size_t)j * 16 * IN_SZ),
                (__attribute__((address_space(3))) uint32_t*)(As + (wave * 32 + j * 16) * 64),
                16, 0, 0);
            __builtin_amdgcn_global_load_lds(
                (const __attribute__((address_space(1))) uint32_t*)(gB + k0 + (size_t)j * 16 * IN_SZ),
                (__attribute__((address_space(3))) uint32_t*)(Bs + (wave * 32 + j * 16) * 64),
                16, 0, 0);
        }
        __syncthreads();

#pragma unroll
        for (int s = 0; s < 2; ++s) {    // two 32-byte k-halves of the 64B row
            int4v a[2], b[2];
#pragma unroll
            for (int i = 0; i < 2; ++i) {
                a[i] = *(const int4v*)(As + (wm + i * 32 + frow) * 64 + s * 32 + fk);
                b[i] = *(const int4v*)(Bs + (wn + i * 32 + frow) * 64 + s * 32 + fk);
            }
#pragma unroll
            for (int i = 0; i < 2; ++i)
#pragma unroll
                for (int j = 0; j < 2; ++j)
                    acc[i][j] = __builtin_amdgcn_mfma_i32_32x32x32_i8(a[i], b[j], acc[i][j], 0, 0, 0);
        }
        __syncthreads();
    }

    // epilogue: 32x32 C/D layout col=lane&31, row=(reg&3)+8*(reg>>2)+4*(lane>>5)
    const int col = lane & 31;
    const int rbase = 4 * (lane >> 5);
#pragma unroll
    for (int j = 0; j < 2; ++j) {
        const int o = tn * 128 + wn + j * 32 + col;
        const float al = alpha[o];
        const float bi = bias[o];
#pragma unroll
        for (int i = 0; i < 2; ++i) {
            const size_t mbase = (size_t)(tm * 128 + wm + i * 32);
#pragma unroll
            for (int r = 0; r < 16; ++r) {
                const int row = (r & 3) + 8 * (r >> 2) + rbase;
                out[(mbase + row) * OUT_SZ + o] = al * (float)acc[i][j][r] + bi;
            }
        }
    }
}

extern "C" void kernel_launch(void* const* d_in, const int* in_sizes, int n_in,
                              void* d_out, int out_size, void* d_ws, size_t ws_size,
                              hipStream_t stream) {
    const float* x    = (const float*)d_in[0];   // [B, IN] fp32
    const float* fp   = (const float*)d_in[1];   // [OUT, IN] fp32
    const float* bias = (const float*)d_in[2];   // [OUT] fp32
    float* out = (float*)d_out;                  // [B, OUT] fp32

    int8_t* xb    = (int8_t*)d_ws;                       // 64 MiB
    int8_t* wb    = xb + (size_t)B_SZ * IN_SZ;           // 16 MiB
    float*  alpha = (float*)(wb + (size_t)OUT_SZ * IN_SZ);

    hipLaunchKernelGGL(wprep_kernel, dim3(OUT_SZ), dim3(256), 0, stream, fp, wb, alpha);
    hipLaunchKernelGGL(xprep_kernel, dim3(B_SZ * IN_SZ / 2048), dim3(256), 0, stream, x, xb);
    hipLaunchKernelGGL(gemm_kernel, dim3(B_SZ / 128, OUT_SZ / 128), dim3(256), 0, stream,
                       xb, wb, alpha, bias, out);
}